// Round 3
// baseline (499.777 us; speedup 1.0000x reference)
//
#include <hip/hip_runtime.h>
#include <hip/hip_bf16.h>

#define NB   64
#define NT   2048
#define NENC 512
#define NDEC 1024
#define NCONV 32
#define NK   31
#define NHID 256
#define NPAD 15

typedef __attribute__((ext_vector_type(8))) short bf16x8;  // 8 bf16 in 4 VGPRs
typedef __attribute__((ext_vector_type(4))) float f32x4;

// ws layout (bytes):
//   0       : W_sw   16 nt x 16 ks x 64 lane x 8 bf16      = 262144
//   262144  : G_sw   16 nt x 64 lane x 8 bf16              = 16384
//   278528  : dec_proj 64 x 256 f32                        = 65536
//   344064  : ctx partials 64 b x 32 blk x 512 f32         = 4194304
//   4538368 : ml pairs 64 b x 32 blk x {m,l} f32           = 16384
//   4554752 : per-b arrival counters, 64 int               = 256
#define WS_WSW 0
#define WS_GSW 262144
#define WS_DEC 278528
#define WS_CTX 344064
#define WS_ML  4538368
#define WS_CNT 4554752

__device__ __forceinline__ short f2b(float f) {  // f32 -> bf16 (RNE)
  unsigned u = __builtin_bit_cast(unsigned, f);
  u += 0x7FFFu + ((u >> 16) & 1u);
  return (short)(u >> 16);
}
__device__ __forceinline__ float blo(unsigned u) {
  return __builtin_bit_cast(float, u << 16);
}
__device__ __forceinline__ float bhi(unsigned u) {
  return __builtin_bit_cast(float, u & 0xFFFF0000u);
}

// ---------------------------------------------------------------- prep ------
// blocks [0,512): W_enc -> bf16 fragments in exact MFMA B-operand order
// blocks [512,544): G[h,k] = sum_c W_att[h,c]*conv_w[c,k] -> B-frag order
// blocks [544,800): dec_proj[b,h], 4 threads per (b,h) (k-quarters)
// block 800: zero the per-b arrival counters for the fused finalize
__global__ __launch_bounds__(256) void prep_kernel(
    const float* __restrict__ W_enc, const float* __restrict__ W_att,
    const float* __restrict__ conv_w, const float* __restrict__ dec_state,
    const float* __restrict__ W_dec, char* __restrict__ ws)
{
  const int tid = threadIdx.x;
  const int blk = blockIdx.x;
  if (blk < 512) {
    int idx = blk * 256 + tid;                       // [0, 131072)
    int j = idx & 7, lane = (idx >> 3) & 63;
    int ks = (idx >> 9) & 15, nt = idx >> 13;
    int h = nt * 16 + (lane & 15);
    int k = ks * 32 + (lane >> 4) * 8 + j;
    ((short*)(ws + WS_WSW))[idx] = f2b(W_enc[h * NENC + k]);
  } else if (blk < 544) {
    int idx = (blk - 512) * 256 + tid;               // [0, 8192)
    int j = idx & 7, lane = (idx >> 3) & 63, nt = idx >> 9;
    int h = nt * 16 + (lane & 15);
    int k = (lane >> 4) * 8 + j;
    float v = 0.f;
    if (k < NK) {
      for (int c = 0; c < NCONV; ++c)
        v += W_att[h * NCONV + c] * conv_w[c * NK + k];
    }
    ((short*)(ws + WS_GSW))[idx] = f2b(v);
  } else if (blk < 800) {
    int idx = (blk - 544) * 256 + tid;               // [0, 65536)
    int bh = idx >> 2, q = idx & 3;                  // (b,h) + k-quarter
    int h = bh & 255, bb = bh >> 8;
    const float4* ds4 = (const float4*)(dec_state + bb * NDEC + q * 256);
    const float4* wd4 = (const float4*)(W_dec + h * NDEC + q * 256);
    float s = 0.f;
#pragma unroll 8
    for (int d = 0; d < 64; ++d) {
      float4 a = ds4[d], w = wd4[d];
      s += a.x * w.x + a.y * w.y + a.z * w.z + a.w * w.w;
    }
    s += __shfl_xor(s, 1);
    s += __shfl_xor(s, 2);
    if (q == 0) ((float*)(ws + WS_DEC))[bh] = s;
  } else {
    if (tid < NB) ((int*)(ws + WS_CNT))[tid] = 0;
  }
}

// -------------------------------------------------------------- energy ------
// block = 256 thr (4 waves), tile M=64 (t), N=256 (h), K=512.
// Software-pipelined in two K-halves (stage phase B overlaps MFMA on phase A),
// flash-style context partial from the resident bf16 LDS tile, and a fused
// last-block-per-b finalize (device-scope counter + threadfence handshake).
__global__ __launch_bounds__(256, 2) void energy_kernel(
    const float* __restrict__ enc, const float* __restrict__ prev,
    const int* __restrict__ text_len, const float* __restrict__ b_enc,
    const float* __restrict__ w_w, const float* __restrict__ w_b,
    char* __restrict__ ws, float* __restrict__ d_out)
{
  const int b = blockIdx.y;
  const int bx = blockIdx.x;
  const int t0 = bx * 64;
  const int len = text_len[b];
  if (t0 >= len) return;           // fully masked tile: contributes nothing
  const int nv = (len + 63) >> 6;  // number of contributing tiles for b

  __shared__ short As[64][512];    // 64 KB, chunk-XOR-swizzled (low 3 bits)

  const int tid = threadIdx.x;
  const int wave = tid >> 6, lane = tid & 63;
  const int col = lane & 15, quad = lane >> 4;

  const short* Wsw = (const short*)(ws + WS_WSW);
  const short* Gsw = (const short*)(ws + WS_GSW);
  const float* dec_proj = (const float*)(ws + WS_DEC);
  float* e_out = d_out + NB * NENC;

  const float* src = enc + ((size_t)b * NT + t0) * NENC;

  // ---- issue phase-A staging loads (k 0..255) into registers ----
  float4 pa[8][2];
#pragma unroll
  for (int it = 0; it < 8; ++it) {
    int cidx = it * 256 + tid;
    int row = cidx >> 5, c = cidx & 31;    // 32 chunks-of-8 per row
    const float4* p = (const float4*)(src + row * NENC + c * 8);
    pa[it][0] = p[0]; pa[it][1] = p[1];
  }

  // ---- conv init (independent of LDS; overlaps phase-A load latency) ----
  f32x4 acc[4][4];
  {
    bf16x8 gf[4];
#pragma unroll
    for (int i = 0; i < 4; ++i)
      gf[i] = ((const bf16x8*)Gsw)[(wave * 4 + i) * 64 + lane];
    const float* pb = prev + b * NT;
#pragma unroll
    for (int mt = 0; mt < 4; ++mt) {
      int t = t0 + mt * 16 + col;          // A-operand row m = lane&15
      bf16x8 pf;
#pragma unroll
      for (int j = 0; j < 8; ++j) {
        int k = quad * 8 + j;              // A-operand k = quad*8+j
        int ti = t + k - NPAD;
        float v = (k < NK && ti >= 0 && ti < NT) ? pb[ti] : 0.f;
        pf[j] = f2b(v);
      }
      f32x4 z = {0.f, 0.f, 0.f, 0.f};
#pragma unroll
      for (int i = 0; i < 4; ++i)
        acc[mt][i] = __builtin_amdgcn_mfma_f32_16x16x32_bf16(pf, gf[i], z, 0, 0, 0);
    }
  }

  // ---- convert + write phase A ----
#pragma unroll
  for (int it = 0; it < 8; ++it) {
    int cidx = it * 256 + tid;
    int row = cidx >> 5, c = cidx & 31;
    float4 v0 = pa[it][0], v1 = pa[it][1];
    bf16x8 o;
    o[0] = f2b(v0.x); o[1] = f2b(v0.y); o[2] = f2b(v0.z); o[3] = f2b(v0.w);
    o[4] = f2b(v1.x); o[5] = f2b(v1.y); o[6] = f2b(v1.z); o[7] = f2b(v1.w);
    int csw = c ^ (row & 7);
    *(bf16x8*)(&As[row][csw * 8]) = o;
  }
  __syncthreads();

  // ---- issue phase-B staging loads (k 256..511) into registers ----
  float4 pb2[8][2];
#pragma unroll
  for (int it = 0; it < 8; ++it) {
    int cidx = it * 256 + tid;
    int row = cidx >> 5, c = (cidx & 31) + 32;
    const float4* p = (const float4*)(src + row * NENC + c * 8);
    pb2[it][0] = p[0]; pb2[it][1] = p[1];
  }

  // ---- K phase 1: ks 0..7 on phase-A LDS (phase-B loads in flight) ----
  bf16x8 bcur[4];
#pragma unroll
  for (int i = 0; i < 4; ++i)
    bcur[i] = ((const bf16x8*)Wsw)[((wave * 4 + i) * 16 + 0) * 64 + lane];
#pragma unroll 2
  for (int ks = 0; ks < 8; ++ks) {
    bf16x8 bnxt[4];
#pragma unroll
    for (int i = 0; i < 4; ++i)
      bnxt[i] = ((const bf16x8*)Wsw)[((wave * 4 + i) * 16 + ks + 1) * 64 + lane];
#pragma unroll
    for (int mt = 0; mt < 4; ++mt) {
      int row = mt * 16 + col;
      int chunk = (ks * 4 + quad) ^ (row & 7);
      bf16x8 af = *(const bf16x8*)(&As[row][chunk * 8]);
#pragma unroll
      for (int i = 0; i < 4; ++i)
        acc[mt][i] = __builtin_amdgcn_mfma_f32_16x16x32_bf16(af, bcur[i], acc[mt][i], 0, 0, 0);
    }
#pragma unroll
    for (int i = 0; i < 4; ++i) bcur[i] = bnxt[i];
  }

  // ---- convert + write phase B ----
#pragma unroll
  for (int it = 0; it < 8; ++it) {
    int cidx = it * 256 + tid;
    int row = cidx >> 5, c = (cidx & 31) + 32;
    float4 v0 = pb2[it][0], v1 = pb2[it][1];
    bf16x8 o;
    o[0] = f2b(v0.x); o[1] = f2b(v0.y); o[2] = f2b(v0.z); o[3] = f2b(v0.w);
    o[4] = f2b(v1.x); o[5] = f2b(v1.y); o[6] = f2b(v1.z); o[7] = f2b(v1.w);
    int csw = c ^ (row & 7);
    *(bf16x8*)(&As[row][csw * 8]) = o;
  }
  __syncthreads();

  // ---- K phase 2: ks 8..15 ----
#pragma unroll 2
  for (int ks = 8; ks < 16; ++ks) {
    bf16x8 bnxt[4];
    int ksn = (ks + 1) & 15;               // wrap: last prefetch harmless
#pragma unroll
    for (int i = 0; i < 4; ++i)
      bnxt[i] = ((const bf16x8*)Wsw)[((wave * 4 + i) * 16 + ksn) * 64 + lane];
#pragma unroll
    for (int mt = 0; mt < 4; ++mt) {
      int row = mt * 16 + col;
      int chunk = (ks * 4 + quad) ^ (row & 7);
      bf16x8 af = *(const bf16x8*)(&As[row][chunk * 8]);
#pragma unroll
      for (int i = 0; i < 4; ++i)
        acc[mt][i] = __builtin_amdgcn_mfma_f32_16x16x32_bf16(af, bcur[i], acc[mt][i], 0, 0, 0);
    }
#pragma unroll
    for (int i = 0; i < 4; ++i) bcur[i] = bnxt[i];
  }

  __syncthreads();                         // all waves done reading As rows
  // save As row 0 (ep/ww will overwrite); sv is exactly the (t=0, c-pair)
  // uint this thread needs in the context loop
  unsigned sv = ((const unsigned*)As)[tid];
  __syncthreads();                         // saves complete before ep writes

  float* ep = (float*)&As[0][0];           // 256 f32 = As row 0
  float* wwp = (float*)&As[0][0];          // ww[64] reuses ep[0..63] after use

  // ---- epilogue: tanh, dot w_w, cross-wave h-reduction ----
  const float* dpb = dec_proj + b * NHID;
  float pre[4], wv[4];
#pragma unroll
  for (int i = 0; i < 4; ++i) {
    int h = (wave * 4 + i) * 16 + col;
    pre[i] = dpb[h] + b_enc[h];
    wv[i] = w_w[h];
  }
#pragma unroll
  for (int mt = 0; mt < 4; ++mt) {
#pragma unroll
    for (int r = 0; r < 4; ++r) {          // C/D: row = quad*4+r, col = lane&15
      float s = 0.f;
#pragma unroll
      for (int i = 0; i < 4; ++i) {
        float x = acc[mt][i][r] + pre[i];
        float e2 = __expf(2.f * x);        // tanh(x) = 1 - 2/(e^2x+1)
        s += wv[i] * (1.f - 2.f / (e2 + 1.f));
      }
      s += __shfl_xor(s, 1);
      s += __shfl_xor(s, 2);
      s += __shfl_xor(s, 4);
      s += __shfl_xor(s, 8);
      if (col == 0) ep[wave * 64 + mt * 16 + quad * 4 + r] = s;
    }
  }
  __syncthreads();

  // ---- wave 0: energies, block max, exp weights, block sum ----
  if (tid < 64) {
    float e = ep[tid] + ep[64 + tid] + ep[128 + tid] + ep[192 + tid] + w_b[0];
    e_out[b * NT + t0 + tid] = e;          // raw energy (finalize rescales)
    float me = (t0 + tid < len) ? e : -3.0e38f;
    float m = me;
#pragma unroll
    for (int o = 1; o < 64; o <<= 1) m = fmaxf(m, __shfl_xor(m, o));
    float w = __expf(me - m);              // masked t -> 0 exactly
    wwp[tid] = w;                          // overwrites ep[tid] after its read
    float l = w;
#pragma unroll
    for (int o = 1; o < 64; o <<= 1) l += __shfl_xor(l, o);
    if (tid == 0) {
      float* ml = (float*)(ws + WS_ML) + (b * 32 + bx) * 2;
      ml[0] = m; ml[1] = l;
    }
  }
  __syncthreads();

  // ---- context partial from resident bf16 tile: ctx[c] = sum_t w_t*A[t,c] --
  {
    const int c0 = tid * 2;
    const int chunk = c0 >> 3, oc = c0 & 7;
    float w0 = wwp[0];
    float a0 = w0 * blo(sv);               // t=0 from the saved register
    float a1 = w0 * bhi(sv);
#pragma unroll 7
    for (int t = 1; t < 64; ++t) {
      float w = wwp[t];                    // broadcast (same addr all lanes)
      unsigned u = *(const unsigned*)(&As[t][((chunk ^ (t & 7)) << 3) + oc]);
      a0 += w * blo(u);
      a1 += w * bhi(u);
    }
    float2 st = {a0, a1};
    *(float2*)((float*)(ws + WS_CTX) + (size_t)(b * 32 + bx) * NENC + c0) = st;
  }

  // ---- fused finalize: last arriving block of this b does it ----
  __syncthreads();                         // drains all global stores (vmcnt)
  int* flg = (int*)&As[0][0];
  if (tid == 0) {
    __threadfence();                       // release: block's stores -> device
    int old = atomicAdd((int*)(ws + WS_CNT) + b, 1);
    int last = (old == nv - 1) ? 1 : 0;
    if (last) __threadfence();             // acquire: see others' stores
    flg[0] = last;
  }
  __syncthreads();
  if (!flg[0]) return;

  float* fsc = (float*)&As[0][0] + 64;     // scale[32] + {m,l}
  if (tid < 64) {
    const float* ml = (const float*)(ws + WS_ML) + b * 64;
    float mi = -3.0e38f, li = 0.f;
    if (tid < nv) { mi = ml[tid * 2]; li = ml[tid * 2 + 1]; }
    float m = mi;
#pragma unroll
    for (int o = 1; o < 64; o <<= 1) m = fmaxf(m, __shfl_xor(m, o));
    float e = __expf(mi - m);              // 0 for invalid lanes
    float l = li * e;
#pragma unroll
    for (int o = 1; o < 64; o <<= 1) l += __shfl_xor(l, o);
    if (tid < 32) fsc[tid] = e;
    if (tid == 0) { fsc[32] = m; fsc[33] = l; }
  }
  __syncthreads();
  const float m = fsc[32], invl = 1.f / fsc[33];

  // att_c[b,c] = sum_i sc[i]*ctx[i][c] / l
  {
    const float* ctx = (const float*)(ws + WS_CTX) + (size_t)b * 32 * NENC;
    float a0 = 0.f, a1 = 0.f;
    for (int i = 0; i < nv; ++i) {
      float s = fsc[i];
      a0 += s * ctx[i * NENC + tid];
      a1 += s * ctx[i * NENC + tid + 256];
    }
    d_out[b * NENC + tid] = a0 * invl;
    d_out[b * NENC + tid + 256] = a1 * invl;
  }

  // att_w[b,t] = exp(e_t - m)/l  (0 beyond len)
  float* aw = e_out + b * NT;
#pragma unroll
  for (int j = 0; j < 8; ++j) {
    int t = tid + j * 256;
    float v = 0.f;
    if (t < len) v = __expf(aw[t] - m) * invl;
    aw[t] = v;
  }
}

// ------------------------------------------------------------------ launch --
extern "C" void kernel_launch(void* const* d_in, const int* in_sizes, int n_in,
                              void* d_out, int out_size, void* d_ws, size_t ws_size,
                              hipStream_t stream)
{
  const float* enc      = (const float*)d_in[0];
  const float* dec_st   = (const float*)d_in[1];
  const float* prev     = (const float*)d_in[2];
  const int*   text_len = (const int*)d_in[3];
  const float* W_enc    = (const float*)d_in[4];
  const float* b_enc    = (const float*)d_in[5];
  const float* W_dec    = (const float*)d_in[6];
  const float* W_att    = (const float*)d_in[7];
  const float* conv_w   = (const float*)d_in[8];
  const float* w_w      = (const float*)d_in[9];
  const float* w_b      = (const float*)d_in[10];
  float* out = (float*)d_out;
  char* ws = (char*)d_ws;

  hipLaunchKernelGGL(prep_kernel, dim3(801), dim3(256), 0, stream,
                     W_enc, W_att, conv_w, dec_st, W_dec, ws);
  hipLaunchKernelGGL(energy_kernel, dim3(32, 64), dim3(256), 0, stream,
                     enc, prev, text_len, b_enc, w_w, w_b, ws, out);
}